// Round 8
// baseline (69.130 us; speedup 1.0000x reference)
//
#include <hip/hip_runtime.h>
#include <math.h>

// (B,T,N,D) = (16,100,128,3), fp32 in, fp32 scalar out.
constexpr int B = 16, T = 100, N = 128;
constexpr float MIN_DIST  = 0.05f;
constexpr float MIN_DIST2 = MIN_DIST * MIN_DIST;

constexpr int THREADS     = 256;
constexpr int MISC_BLOCKS = 160;              // scheduled first (streaming)
constexpr int PEN_BLOCKS  = B * T;            // 1600 — one (b,t) slice per block
constexpr int TOTAL_BLOCKS = MISC_BLOCKS + PEN_BLOCKS;

constexpr int PER_B = T * N * 3;              // 38400 floats per batch
constexpr int PER_T = N * 3;                  // 384 floats per slice

constexpr int WORK_V4_PER_B = (T - 1) * N * 3 / 4;    // 9504
constexpr int WORK_V4 = B * WORK_V4_PER_B;            // 152064
constexpr int KE_V4_PER_SLICE = N * 3 / 4;            // 96
constexpr int KE_V4  = 2 * B * KE_V4_PER_SLICE;       // 3072
constexpr int STAB_V = B * 5 * N;                     // 10240
constexpr int MISC_TOTAL = WORK_V4 + STAB_V + KE_V4;  // 165376

constexpr int WORK_N = B * (T - 1) * N;               // 202752 (mean divisor)

// ws layout (every slot written every call -> no zero-init node):
constexpr int WORK_OFF = 1600, STAB_OFF = 1760, KE0_OFF = 1920, KE1_OFF = 2080;

__device__ __forceinline__ float wave_sum(float v) {
#pragma unroll
    for (int off = 32; off > 0; off >>= 1) v += __shfl_down(v, off, 64);
    return v;
}

__global__ __launch_bounds__(THREADS) void physics_fused(
    const float* __restrict__ traj, const float* __restrict__ vel,
    const float* __restrict__ frc, float* __restrict__ ws)
{
    __shared__ float  sraw[PER_T];     // 384 floats raw slice
    __shared__ float4 spos[N];         // 128 padded points; tile t = spos[4t..4t+3]
    __shared__ float  red[4][4];

    const int tid  = threadIdx.x;
    const int bid  = blockIdx.x;
    const int lane = tid & 63;
    const int wv   = tid >> 6;

    if (bid >= MISC_BLOCKS) {
        // ---- penetration: tile-of-4 scheme, 16 pairs per 4 LDS reads ----
        const int pb = bid - MISC_BLOCKS;
        if (tid < PER_T / 4)
            ((float4*)sraw)[tid] = ((const float4*)traj)[pb * (PER_T / 4) + tid];
        __syncthreads();
        if (tid < N)
            spos[tid] = make_float4(sraw[3 * tid], sraw[3 * tid + 1], sraw[3 * tid + 2], 0.f);
        __syncthreads();

        const int t = lane & 31;       // owned tile
        const int h = lane >> 5;       // half selects m-offsets
        float4 own[4];
#pragma unroll
        for (int p = 0; p < 4; ++p) own[p] = spos[4 * t + p];

        float s = 0.f;
        // inter-tile: wave wv, half h covers m = {4wv+2h+1, 4wv+2h+2} -> m = 1..16
#pragma unroll
        for (int it = 0; it < 2; ++it) {
            const int m = 4 * wv + 2 * h + 1 + it;
            const int u = (t + m) & 31;
            const bool valid = (m < 16) | (t < 16);   // m=16 counted for t<16 only
            float4 part[4];
#pragma unroll
            for (int p = 0; p < 4; ++p) part[p] = spos[4 * u + p];
            float dmin = 1e30f;
#pragma unroll
            for (int p = 0; p < 4; ++p)
#pragma unroll
                for (int q = 0; q < 4; ++q) {
                    const float dx = own[p].x - part[q].x;
                    const float dy = own[p].y - part[q].y;
                    const float dz = own[p].z - part[q].z;
                    dmin = fminf(dmin, dx * dx + dy * dy + dz * dz);
                }
            const bool hit = valid & (dmin < MIN_DIST2);
            if (__builtin_expect(__any(hit), 0)) {    // hits ~1e-5/pair
#pragma unroll
                for (int p = 0; p < 4; ++p)
#pragma unroll
                    for (int q = 0; q < 4; ++q) {
                        const float dx = own[p].x - part[q].x;
                        const float dy = own[p].y - part[q].y;
                        const float dz = own[p].z - part[q].z;
                        const float d2 = dx * dx + dy * dy + dz * dz;
                        if (valid && d2 < MIN_DIST2) s += MIN_DIST - sqrtf(d2);
                    }
            }
        }
        // intra-tile pairs (6 per tile), wave 0 only; branchless pair select
        if (wv == 0) {
            const float4 a0 = h ? own[1] : own[0], b0 = h ? own[2] : own[1];
            const float4 a1 = h ? own[1] : own[0], b1 = h ? own[3] : own[2];
            const float4 a2 = h ? own[2] : own[0], b2 = h ? own[3] : own[3];
            float dx = a0.x - b0.x, dy = a0.y - b0.y, dz = a0.z - b0.z;
            const float d20 = dx * dx + dy * dy + dz * dz;
            dx = a1.x - b1.x; dy = a1.y - b1.y; dz = a1.z - b1.z;
            const float d21 = dx * dx + dy * dy + dz * dz;
            dx = a2.x - b2.x; dy = a2.y - b2.y; dz = a2.z - b2.z;
            const float d22 = dx * dx + dy * dy + dz * dz;
            const float dmin = fminf(d20, fminf(d21, d22));
            if (__builtin_expect(__any(dmin < MIN_DIST2), 0)) {
                if (d20 < MIN_DIST2) s += MIN_DIST - sqrtf(d20);
                if (d21 < MIN_DIST2) s += MIN_DIST - sqrtf(d21);
                if (d22 < MIN_DIST2) s += MIN_DIST - sqrtf(d22);
            }
        }

        float w = wave_sum(s);
        if (lane == 0) red[0][wv] = w;
        __syncthreads();
        if (tid == 0)
            ws[pb] = red[0][0] + red[0][1] + red[0][2] + red[0][3];
    } else {
        // ---- work / stability / kinetic: vectorized grid-stride ----
        const int mb = bid;
        const float4* t4 = (const float4*)traj;
        const float4* f4 = (const float4*)frc;
        const float4* v4 = (const float4*)vel;
        float sw = 0.f, ss = 0.f, k0 = 0.f, k1 = 0.f;
        const int stride = MISC_BLOCKS * THREADS;
        for (int v = mb * THREADS + tid; v < MISC_TOTAL; v += stride) {
            if (v < WORK_V4) {
                const int b = v / WORK_V4_PER_B;
                const int r = v - b * WORK_V4_PER_B;
                const int base = b * (PER_B / 4) + r;
                const float4 f  = f4[base];
                const float4 t0 = t4[base];
                const float4 t1 = t4[base + PER_T / 4];
                sw += f.x * (t1.x - t0.x) + f.y * (t1.y - t0.y)
                    + f.z * (t1.z - t0.z) + f.w * (t1.w - t0.w);
            } else if (v < WORK_V4 + STAB_V) {
                const int s2 = v - WORK_V4;
                const int b  = s2 / 640;           // 5*N vectors per batch
                const int r  = s2 - b * 640;
                const int e  = b * PER_B + 95 * PER_T + r * 3;
                const float vx = vel[e], vy = vel[e + 1], vz = vel[e + 2];
                ss += sqrtf(vx * vx + vy * vy + vz * vz);
            } else {
                const int s2    = v - WORK_V4 - STAB_V;      // [0,3072)
                const int which = s2 / 1536;                 // 0 -> t=0, 1 -> t=T-1
                const int rr    = s2 - which * 1536;
                const int b     = rr / KE_V4_PER_SLICE;
                const int r     = rr - b * KE_V4_PER_SLICE;
                const float4 q  = v4[b * (PER_B / 4) + which * (99 * PER_T / 4) + r];
                const float k   = q.x * q.x + q.y * q.y + q.z * q.z + q.w * q.w;
                if (which) k1 += k; else k0 += k;
            }
        }
        float vals[4] = {sw, ss, k0, k1};
#pragma unroll
        for (int vv = 0; vv < 4; ++vv) {
            const float w = wave_sum(vals[vv]);
            if (lane == 0) red[vv][wv] = w;
        }
        __syncthreads();
        if (tid == 0) {
            ws[WORK_OFF + mb] = red[0][0] + red[0][1] + red[0][2] + red[0][3];
            ws[STAB_OFF + mb] = red[1][0] + red[1][1] + red[1][2] + red[1][3];
            ws[KE0_OFF  + mb] = red[2][0] + red[2][1] + red[2][2] + red[2][3];
            ws[KE1_OFF  + mb] = red[3][0] + red[3][1] + red[3][2] + red[3][3];
        }
    }
}

__global__ __launch_bounds__(256) void physics_finalize(
    const float* __restrict__ ws, float* __restrict__ out)
{
    __shared__ float redP[4], redM[4];
    const int tid = threadIdx.x, lane = tid & 63, wv = tid >> 6;

    float p = 0.f;
    for (int i = tid; i < PEN_BLOCKS; i += 256) p += ws[i];

    const int base = WORK_OFF + 160 * wv;   // wave wv: work/stab/ke0/ke1 segment
    float m = ws[base + lane] + ws[base + 64 + lane]
            + (lane < 32 ? ws[base + 128 + lane] : 0.f);

    p = wave_sum(p);
    m = wave_sum(m);
    if (lane == 0) { redP[wv] = p; redM[wv] = m; }
    __syncthreads();

    if (tid == 0) {
        const float pen = redP[0] + redP[1] + redP[2] + redP[3];
        const float wk = redM[0], st = redM[1], k0 = redM[2], k1 = redM[3];
        const float pen_loss  = pen / (float)((long long)B * T * (N * (N - 1) / 2));
        const float stab_loss = st / (float)STAB_V;
        const float ke_s = 0.5f * k0 / (float)(B * N);
        const float ke_e = 0.5f * k1 / (float)(B * N);
        const float work = wk / (float)WORK_N;
        out[0] = 10.0f * pen_loss + stab_loss + 0.1f * fabsf(ke_e - ke_s - work);
    }
}

extern "C" void kernel_launch(void* const* d_in, const int* in_sizes, int n_in,
                              void* d_out, int out_size, void* d_ws, size_t ws_size,
                              hipStream_t stream) {
    const float* traj = (const float*)d_in[0];
    const float* vel  = (const float*)d_in[1];
    const float* frc  = (const float*)d_in[2];
    float* out = (float*)d_out;
    float* ws  = (float*)d_ws;

    physics_fused<<<TOTAL_BLOCKS, THREADS, 0, stream>>>(traj, vel, frc, ws);
    physics_finalize<<<1, 256, 0, stream>>>(ws, out);
}